// Round 12
// baseline (42.493 us; speedup 1.0000x reference)
//
#include <hip/hip_runtime.h>

// R12 ABLATION: dispatch1 = v11 with runtime-never store predicate (all
// DMA/LDS/VALU live, zero store traffic; predicate is runtime-uniform so
// nothing is DCE'd and the branch is a cheap execz skip). dispatch2 = real
// v11 (correct output). T_readside = dur_us - 30.0 (R11 baseline).
//   T_c <= 15us -> overlap/backpressure problem; T_c >= 22us -> CU-side
//   (LDS) wall; between -> mixed.

typedef float f32x4 __attribute__((ext_vector_type(4)));

constexpr int C_DIM = 256;
constexpr int H_DIM = 50;
constexpr int W_DIM = 50;
constexpr int M_BOX = 512;
constexpr int CW    = 14;
constexpr int CCH   = 16;             // channels per block (4 waves x 4)
constexpr int NPOS  = 196;
constexpr int PLANE  = H_DIM * W_DIM; // 2500
constexpr int WC  = 16;               // window cols
constexpr int WSZ = 256;              // 16x16 window floats per plane
constexpr float INV_STRIDE = 1.0f / 16.0f;

template <bool NEVER_STORE>
__global__ __launch_bounds__(256) void roi_align_v12(
    const float* __restrict__ fm,
    const float* __restrict__ boxes,
    const int*   __restrict__ box_idx,
    float*       __restrict__ out)
{
    __shared__ float Wnd[CCH * WSZ];  // 16 KB -> 8 blocks/CU

    // Channel-slab XCD mapping (R9): XCD k = bid&7 owns channels [32k, 32k+32).
    int bid   = blockIdx.x;
    int xcd   = bid & 7;
    int w     = bid >> 3;             // [0,1024)
    int m     = w >> 1;               // box
    int cbase = xcd * 32 + (w & 1) * CCH;

    int t  = threadIdx.x;
    int wv = t >> 6;                  // wave 0..3 -> channels cbase+4wv..+3
    int l  = t & 63;

    float4 bx = reinterpret_cast<const float4*>(boxes)[m];
    int bi = box_idx[m];
    float x1 = bx.x * INV_STRIDE;
    float y1 = bx.y * INV_STRIDE;
    float x2 = bx.z * INV_STRIDE;
    float y2 = bx.w * INV_STRIDE;

    int xLo = min(max((int)floorf(x1), 0), W_DIM - 1);
    int yLo = min(max((int)floorf(y1), 0), H_DIM - 1);
    int xW  = min(xLo, W_DIM - WC);   // window cols xW..xW+15 always in-bounds

    // ---- Phase A: wave stages ITS OWN 4 plane-windows (async DMA) ----
    {
        int row  = l >> 2;            // 0..15
        int quad = l & 3;             // cols 4quad..4quad+3
        int gy   = min(yLo + row, H_DIM - 1);   // row clamp-duplicate
        const float* g0 = fm + ((size_t)(bi * C_DIM + cbase + wv * 4)) * PLANE
                             + gy * W_DIM + xW + quad * 4;
        #pragma unroll
        for (int k = 0; k < 4; ++k) {
            const float* g  = g0 + (size_t)k * PLANE;
            float*       l0 = &Wnd[(wv * 4 + k) * WSZ];  // wave-uniform base
            __builtin_amdgcn_global_load_lds(
                (const __attribute__((address_space(1))) unsigned int*)g,
                (__attribute__((address_space(3))) unsigned int*)l0,
                16, 0, 0);
        }
    }

    // ---- Phase B: lanes 0..48 each own a position-quad x wave's 4 channels ----
    if (l < 49) {
        int q = l;                    // quad -> positions 4q..4q+3

        int   w00[4];
        float wxv[4], owx[4], wyv[4], owy[4];
        #pragma unroll
        for (int e = 0; e < 4; ++e) {
            int p  = 4 * q + e;
            int iy = p / CW;
            int ix = p - iy * CW;
            float ys = y1 + ((float)iy * (y2 - y1)) / 13.0f;
            float xs = x1 + ((float)ix * (x2 - x1)) / 13.0f;
            float y0f = floorf(ys);
            float x0f = floorf(xs);
            float wy = ys - y0f;
            float wx = xs - x0f;
            int y0i = min(max((int)y0f, 0), H_DIM - 1);
            int x0i = min(max((int)x0f, 0), W_DIM - 1);
            bool vld = (ys >= 0.0f) && (ys <= (float)(H_DIM - 1)) &&
                       (xs >= 0.0f) && (xs <= (float)(W_DIM - 1));
            w00[e] = (y0i - yLo) * WC + (x0i - xW);
            wxv[e] = vld ? wx : 0.0f;
            owx[e] = vld ? (1.0f - wx) : 0.0f;
            wyv[e] = wy; owy[e] = 1.0f - wy;
        }

        // wait for THIS WAVE's 4 DMA loads only
        asm volatile("s_waitcnt vmcnt(0)" ::: "memory");

        // runtime-uniform predicate: boxes are in [0,600+199] so bx.x<-1e30
        // is never true -- compiler can't know that, so nothing is DCE'd;
        // at runtime the store branch is an execz skip.
        bool do_store = NEVER_STORE ? (bx.x < -1e30f) : true;

        const float* wp = &Wnd[(size_t)(wv * 4) * WSZ];
        float* op = out + ((size_t)m * C_DIM + cbase + wv * 4) * NPOS + 4 * q;

        #pragma unroll
        for (int k = 0; k < 4; ++k) {
            float rv[4];
            #pragma unroll
            for (int e = 0; e < 4; ++e) {
                float f00 = wp[w00[e]];
                float f01 = wp[w00[e] + 1];
                float f10 = wp[w00[e] + WC];
                float f11 = wp[w00[e] + WC + 1];
                float top = f00 * owx[e] + f01 * wxv[e];
                float bot = f10 * owx[e] + f11 * wxv[e];
                rv[e] = top * owy[e] + bot * wyv[e];
            }
            if (do_store) {
                f32x4 r;
                r.x = rv[0]; r.y = rv[1]; r.z = rv[2]; r.w = rv[3];
                __builtin_nontemporal_store(r, reinterpret_cast<f32x4*>(op));
            }
            wp += WSZ;
            op += NPOS;
        }
    }
}

extern "C" void kernel_launch(void* const* d_in, const int* in_sizes, int n_in,
                              void* d_out, int out_size, void* d_ws, size_t ws_size,
                              hipStream_t stream) {
    const float* fm      = (const float*)d_in[0];
    const float* boxes   = (const float*)d_in[1];
    const int*   box_idx = (const int*)d_in[2];
    float* out = (float*)d_out;

    dim3 block(256);
    dim3 grid(M_BOX * (C_DIM / CCH) /* 8192 */);
    // 1) read/compute-side probe (no store traffic, output untouched)
    hipLaunchKernelGGL(roi_align_v12<true>, grid, block, 0, stream,
                       fm, boxes, box_idx, out);
    // 2) real kernel (correct output)
    hipLaunchKernelGGL(roi_align_v12<false>, grid, block, 0, stream,
                       fm, boxes, box_idx, out);
}

// Round 13
// 35.687 us; speedup vs baseline: 1.1907x; 1.1907x over previous
//
#include <hip/hip_runtime.h>

// RoiAlign: fm (4,256,50,50) f32, boxes (512,4), box_idx (512) -> out (512,256,14,14) f32
//
// R13: block-level software pipeline. R12 probe: read/compute alone = 12.5us,
// store stream alone = 17.1us (R7), full kernel = 30.0 = SUM -> zero overlap
// (phase-bursty: stage -> compute -> store-burst). Fix: persistent blocks,
// grid=2048 (exactly 8 blocks/CU, one generation), each block runs 8 items
// (2 boxes x 4 sub-slabs of 8 channels) with double-buffered LDS (2x8KB) and
// COUNTED vmcnt waits (never 0 in the loop, T4 pattern):
//   prologue: DMA item0
//   iter j:   DMA item j+1 -> s_waitcnt vmcnt(4) [j's DMA done; j-1's stores
//             and j+1's DMA stay in flight] -> compute+store item j
// Store drain of item j overlaps DMA+compute of item j+1 continuously.
// Keeps R9 channel-slab XCD tiling (XCD k owns channels [32k,32k+32) for all
// boxes -> 1.28MB L2-resident slab). Weights recomputed once per box (j=0,4),
// in the DMA-latency shadow. Wave wv owns 2 planes/item; lanes 0..48 own one
// position-quad; taps at w00+{0,1,16,17}; validity folded into x-weights;
// quad dwordx4 NT stores.

typedef float f32x4 __attribute__((ext_vector_type(4)));

constexpr int C_DIM = 256;
constexpr int H_DIM = 50;
constexpr int W_DIM = 50;
constexpr int M_BOX = 512;
constexpr int CW    = 14;
constexpr int NPOS  = 196;
constexpr int PLANE = H_DIM * W_DIM;  // 2500
constexpr int WC    = 16;             // window cols
constexpr int WSZ   = 256;            // 16x16 floats per plane window
constexpr int ITEM_CH = 8;            // channels per item (2 per wave)
constexpr float INV_STRIDE = 1.0f / 16.0f;

struct SC { int bi, yLo, xW; float x1, y1, x2, y2; };
struct WT { int w00[4]; float wx[4], ox[4], wy[4], oy[4]; };

__device__ __forceinline__ SC mk_sc(const float* boxes, const int* bidx, int m) {
    float4 bx = reinterpret_cast<const float4*>(boxes)[m];
    SC s;
    s.bi = bidx[m];
    s.x1 = bx.x * INV_STRIDE; s.y1 = bx.y * INV_STRIDE;
    s.x2 = bx.z * INV_STRIDE; s.y2 = bx.w * INV_STRIDE;
    int xLo = min(max((int)floorf(s.x1), 0), W_DIM - 1);
    s.yLo = min(max((int)floorf(s.y1), 0), H_DIM - 1);
    s.xW  = min(xLo, W_DIM - WC);     // window cols xW..xW+15 in-bounds
    return s;
}

__device__ __forceinline__ void mk_wt(const SC& s, int q, WT& W) {
    #pragma unroll
    for (int e = 0; e < 4; ++e) {
        int p  = 4 * q + e;
        int iy = p / CW;
        int ix = p - iy * CW;
        // reference op order: v1 + (i * (v2-v1)) / 13
        float ys = s.y1 + ((float)iy * (s.y2 - s.y1)) / 13.0f;
        float xs = s.x1 + ((float)ix * (s.x2 - s.x1)) / 13.0f;
        float y0f = floorf(ys);
        float x0f = floorf(xs);
        float wy = ys - y0f;
        float wx = xs - x0f;
        int y0i = min(max((int)y0f, 0), H_DIM - 1);
        int x0i = min(max((int)x0f, 0), W_DIM - 1);
        bool v = (ys >= 0.0f) && (ys <= (float)(H_DIM - 1)) &&
                 (xs >= 0.0f) && (xs <= (float)(W_DIM - 1));
        W.w00[e] = (y0i - s.yLo) * WC + (x0i - s.xW);
        W.wx[e] = v ? wx : 0.0f;            // invalid -> both x-weights 0 -> exact 0
        W.ox[e] = v ? (1.0f - wx) : 0.0f;
        W.wy[e] = wy; W.oy[e] = 1.0f - wy;
    }
}

__device__ __forceinline__ void stage(const float* fm, const SC& s, int cb,
                                      int wv, int l, float* buf) {
    int row  = l >> 2;                      // 0..15
    int quad = l & 3;                       // cols 4quad..4quad+3
    int gy   = min(s.yLo + row, H_DIM - 1); // row clamp-duplicate
    const float* g0 = fm + ((size_t)(s.bi * C_DIM + cb + wv * 2)) * PLANE
                         + gy * W_DIM + s.xW + quad * 4;
    float* l0 = &buf[(wv * 2) * WSZ];       // wave-uniform base
    __builtin_amdgcn_global_load_lds(
        (const __attribute__((address_space(1))) unsigned int*)g0,
        (__attribute__((address_space(3))) unsigned int*)l0, 16, 0, 0);
    __builtin_amdgcn_global_load_lds(
        (const __attribute__((address_space(1))) unsigned int*)(g0 + PLANE),
        (__attribute__((address_space(3))) unsigned int*)(l0 + WSZ), 16, 0, 0);
}

__device__ __forceinline__ void comp(const float* buf, const WT& W, float* out,
                                     int m, int cb, int wv, int q) {
    const float* wp = &buf[(wv * 2) * WSZ];
    float* op = out + ((size_t)m * C_DIM + cb + wv * 2) * NPOS + 4 * q;
    #pragma unroll
    for (int k = 0; k < 2; ++k) {
        float rv[4];
        #pragma unroll
        for (int e = 0; e < 4; ++e) {
            float f00 = wp[W.w00[e]];
            float f01 = wp[W.w00[e] + 1];
            float f10 = wp[W.w00[e] + WC];
            float f11 = wp[W.w00[e] + WC + 1];
            float top = f00 * W.ox[e] + f01 * W.wx[e];
            float bot = f10 * W.ox[e] + f11 * W.wx[e];
            rv[e] = top * W.oy[e] + bot * W.wy[e];
        }
        f32x4 r;
        r.x = rv[0]; r.y = rv[1]; r.z = rv[2]; r.w = rv[3];
        __builtin_nontemporal_store(r, reinterpret_cast<f32x4*>(op));
        wp += WSZ;
        op += NPOS;
    }
}

__global__ __launch_bounds__(256, 8) void roi_align_v13(
    const float* __restrict__ fm,
    const float* __restrict__ boxes,
    const int*   __restrict__ box_idx,
    float*       __restrict__ out)
{
    __shared__ float B0[ITEM_CH * WSZ];   // 8 KB
    __shared__ float B1[ITEM_CH * WSZ];   // 8 KB  (16 KB total -> 8 blocks/CU)

    int bid  = blockIdx.x;
    int xcd  = bid & 7;                   // R9 slab: XCD k owns ch [32k,32k+32)
    int bxl  = bid >> 3;                  // 0..255
    int cb_x = xcd * 32;
    int m0   = 2 * bxl;
    int m1   = m0 + 1;

    int t  = threadIdx.x;
    int wv = t >> 6;                      // wave 0..3 -> planes 2wv,2wv+1
    int l  = t & 63;
    int q  = l;                           // position-quad (lanes 0..48)
    int qq = min(l, 48);                  // uniform-flow weight calc for all lanes

    SC s0 = mk_sc(boxes, box_idx, m0);
    SC s1;
    WT W;
    mk_wt(s0, qq, W);

    // prologue: stage item 0 (box0, sub-slab 0)
    stage(fm, s0, cb_x + 0, wv, l, B0);

    #pragma unroll
    for (int j = 0; j < 8; ++j) {
        float* bc = (j & 1) ? B1 : B0;
        float* bn = (j & 1) ? B0 : B1;
        int mcur  = (j < 4) ? m0 : m1;
        int cb    = cb_x + (j & 3) * ITEM_CH;

        if (j == 3) s1 = mk_sc(boxes, box_idx, m1);   // before item-4 prefetch

        if (j < 7) {                                   // prefetch item j+1
            int jn = j + 1;
            stage(fm, (jn < 4) ? s0 : s1, cb_x + (jn & 3) * ITEM_CH, wv, l, bn);
        }

        if (j == 4) mk_wt(s1, qq, W);   // box1 weights, in DMA-latency shadow

        // counted wait: only item j's 2 DMAs must be done; item j-1's 2 stores
        // and item j+1's 2 DMAs stay in flight (vmcnt retires in order).
        if (j == 0 || j == 7) {
            asm volatile("s_waitcnt vmcnt(2)" ::: "memory");
        } else {
            asm volatile("s_waitcnt vmcnt(4)" ::: "memory");
        }

        if (l < 49) comp(bc, W, out, mcur, cb, wv, q);
    }
}

extern "C" void kernel_launch(void* const* d_in, const int* in_sizes, int n_in,
                              void* d_out, int out_size, void* d_ws, size_t ws_size,
                              hipStream_t stream) {
    const float* fm      = (const float*)d_in[0];
    const float* boxes   = (const float*)d_in[1];
    const int*   box_idx = (const int*)d_in[2];
    float* out = (float*)d_out;

    dim3 block(256);
    dim3 grid(2048);   // 256 CU x 8 blocks: one generation, no launch bursts
    hipLaunchKernelGGL(roi_align_v13, grid, block, 0, stream,
                       fm, boxes, box_idx, out);
}

// Round 15
// 30.742 us; speedup vs baseline: 1.3823x; 1.1609x over previous
//
#include <hip/hip_runtime.h>

// RoiAlign: fm (4,256,50,50) f32, boxes (512,4), box_idx (512) -> out (512,256,14,14) f32
//
// R14b: == R11 (best, 30.0us) + one-time PHASE STAGGER. (R14 = compile fix:
// restore dropped NPOS constexpr.)
// Evidence: R12 differencing = perfect additivity (store 17.1 + read/compute
// 12.5 = 30.0 full) -> zero overlap. Cause (refined): all 32 waves/CU start
// simultaneously with identical phase structure -> CU-wide convoy: stores
// only flow ~half the wall clock. R13's per-wave counted-vmcnt pipeline
// REGRESSED (35.7) because vmcnt retires in order -> waits coupled compute to
// store-ack latency. Correct fix: desynchronize wave phases once at kernel
// start; offsets self-sustain through block backfill (uniform generation
// length). Stagger = slot * s_sleep(1) (~75cy apart, <=0.83us one-time),
// only for first-generation blocks (bid<2048), placed AFTER DMA issue so the
// sleep overlaps DMA flight.
// Everything else == R11: R9 channel-slab XCD tiling (XCD k owns channels
// [32k,32k+32) for all boxes -> 1.28MB L2-resident slab); wave-autonomous
// staging via global_load_lds(16B) + own vmcnt(0); taps at w00+{0,1,16,17};
// validity folded into x-weights; quad dwordx4 NT stores.

typedef float f32x4 __attribute__((ext_vector_type(4)));

constexpr int C_DIM = 256;
constexpr int H_DIM = 50;
constexpr int W_DIM = 50;
constexpr int M_BOX = 512;
constexpr int CW    = 14;
constexpr int NPOS  = 196;            // 14*14 output positions
constexpr int CCH   = 16;             // channels per block (4 waves x 4)
constexpr int PLANE  = H_DIM * W_DIM; // 2500
constexpr int WC  = 16;               // window cols
constexpr int WSZ = 256;              // 16x16 window floats per plane
constexpr float INV_STRIDE = 1.0f / 16.0f;

__global__ __launch_bounds__(256) void roi_align_v14(
    const float* __restrict__ fm,
    const float* __restrict__ boxes,
    const int*   __restrict__ box_idx,
    float*       __restrict__ out)
{
    __shared__ float Wnd[CCH * WSZ];  // 16 KB -> 8 blocks/CU

    // Channel-slab XCD mapping (R9): XCD k = bid&7 owns channels [32k, 32k+32).
    int bid   = blockIdx.x;
    int xcd   = bid & 7;
    int w     = bid >> 3;             // [0,1024)
    int m     = w >> 1;               // box
    int cbase = xcd * 32 + (w & 1) * CCH;

    int t  = threadIdx.x;
    int wv = t >> 6;                  // wave 0..3 -> channels cbase+4wv..+3
    int l  = t & 63;

    float4 bx = reinterpret_cast<const float4*>(boxes)[m];
    int bi = box_idx[m];
    float x1 = bx.x * INV_STRIDE;
    float y1 = bx.y * INV_STRIDE;
    float x2 = bx.z * INV_STRIDE;
    float y2 = bx.w * INV_STRIDE;

    int xLo = min(max((int)floorf(x1), 0), W_DIM - 1);
    int yLo = min(max((int)floorf(y1), 0), H_DIM - 1);
    int xW  = min(xLo, W_DIM - WC);   // window cols xW..xW+15 always in-bounds

    // ---- Phase A: wave stages ITS OWN 4 plane-windows (async DMA) ----
    {
        int row  = l >> 2;            // 0..15
        int quad = l & 3;             // cols 4quad..4quad+3
        int gy   = min(yLo + row, H_DIM - 1);   // row clamp-duplicate
        const float* g0 = fm + ((size_t)(bi * C_DIM + cbase + wv * 4)) * PLANE
                             + gy * W_DIM + xW + quad * 4;
        #pragma unroll
        for (int k = 0; k < 4; ++k) {
            const float* g  = g0 + (size_t)k * PLANE;
            float*       l0 = &Wnd[(wv * 4 + k) * WSZ];  // wave-uniform base
            __builtin_amdgcn_global_load_lds(
                (const __attribute__((address_space(1))) unsigned int*)g,
                (__attribute__((address_space(3))) unsigned int*)l0,
                16, 0, 0);
        }
    }

    // ---- one-time phase stagger (first generation only) ----
    // Desynchronize the 32 waves/CU so store phases tile the timeline; the
    // offsets persist through backfill. Sleep overlaps the DMA flight above.
    if (bid < 2048) {
        int slot = (((bid >> 3) & 7) << 2) | wv;   // 0..31, ~75cy apart
        for (int i = 0; i < slot; ++i)
            asm volatile("s_sleep 1");
    }

    // ---- Phase B: lanes 0..48 each own a position-quad x wave's 4 channels ----
    if (l < 49) {
        int q = l;                    // quad -> positions 4q..4q+3

        int   w00[4];
        float wxv[4], owx[4], wyv[4], owy[4];
        #pragma unroll
        for (int e = 0; e < 4; ++e) {
            int p  = 4 * q + e;
            int iy = p / CW;
            int ix = p - iy * CW;
            // reference op order: v1 + (i * (v2-v1)) / 13
            float ys = y1 + ((float)iy * (y2 - y1)) / 13.0f;
            float xs = x1 + ((float)ix * (x2 - x1)) / 13.0f;
            float y0f = floorf(ys);
            float x0f = floorf(xs);
            float wy = ys - y0f;
            float wx = xs - x0f;
            int y0i = min(max((int)y0f, 0), H_DIM - 1);
            int x0i = min(max((int)x0f, 0), W_DIM - 1);
            bool vld = (ys >= 0.0f) && (ys <= (float)(H_DIM - 1)) &&
                       (xs >= 0.0f) && (xs <= (float)(W_DIM - 1));
            w00[e] = (y0i - yLo) * WC + (x0i - xW);
            // fold validity into x-weights: invalid -> both 0 -> exact 0
            wxv[e] = vld ? wx : 0.0f;
            owx[e] = vld ? (1.0f - wx) : 0.0f;
            wyv[e] = wy; owy[e] = 1.0f - wy;
        }

        // wait for THIS WAVE's 4 DMA loads only (no cross-wave drain)
        asm volatile("s_waitcnt vmcnt(0)" ::: "memory");

        const float* wp = &Wnd[(size_t)(wv * 4) * WSZ];
        float* op = out + ((size_t)m * C_DIM + cbase + wv * 4) * NPOS + 4 * q;

        #pragma unroll
        for (int k = 0; k < 4; ++k) {
            float rv[4];
            #pragma unroll
            for (int e = 0; e < 4; ++e) {
                float f00 = wp[w00[e]];
                float f01 = wp[w00[e] + 1];
                float f10 = wp[w00[e] + WC];
                float f11 = wp[w00[e] + WC + 1];
                float top = f00 * owx[e] + f01 * wxv[e];
                float bot = f10 * owx[e] + f11 * wxv[e];
                rv[e] = top * owy[e] + bot * wyv[e];
            }
            f32x4 r;
            r.x = rv[0]; r.y = rv[1]; r.z = rv[2]; r.w = rv[3];
            __builtin_nontemporal_store(r, reinterpret_cast<f32x4*>(op));
            wp += WSZ;
            op += NPOS;
        }
    }
}

extern "C" void kernel_launch(void* const* d_in, const int* in_sizes, int n_in,
                              void* d_out, int out_size, void* d_ws, size_t ws_size,
                              hipStream_t stream) {
    const float* fm      = (const float*)d_in[0];
    const float* boxes   = (const float*)d_in[1];
    const int*   box_idx = (const int*)d_in[2];
    float* out = (float*)d_out;

    dim3 block(256);
    dim3 grid(M_BOX * (C_DIM / CCH) /* 8192 */);
    hipLaunchKernelGGL(roi_align_v14, grid, block, 0, stream,
                       fm, boxes, box_idx, out);
}